// Round 1
// baseline (415.535 us; speedup 1.0000x reference)
//
#include <hip/hip_runtime.h>
#include <hip/hip_bf16.h>

#define NB 128
#define LL 512
#define DD 512
#define BM 64

typedef __attribute__((ext_vector_type(4))) float  f32x4;
typedef __attribute__((ext_vector_type(8))) short  s16x8;
typedef __attribute__((ext_vector_type(4))) short  s16x4;

__device__ __forceinline__ short f2bf(float f) {
    __hip_bfloat16 h = __float2bfloat16(f);
    return *reinterpret_cast<short*>(&h);
}

// monotone float<->uint mapping so atomicMax(uint) == float max
__device__ __forceinline__ unsigned fmap(float f) {
    unsigned u = __float_as_uint(f);
    return (u & 0x80000000u) ? ~u : (u | 0x80000000u);
}
__device__ __forceinline__ float funmap(unsigned u) {
    unsigned b = (u & 0x80000000u) ? (u ^ 0x80000000u) : ~u;
    return __uint_as_float(b);
}

// one wave per row: fp32 sum-of-squares -> inv norm (clamped at 1e-8 like torch/jax ref)
__global__ __launch_bounds__(256) void norms_kernel(
        const float* __restrict__ x1, const float* __restrict__ x2,
        float* __restrict__ inv1, float* __restrict__ inv2) {
    int row  = blockIdx.x * 4 + (threadIdx.x >> 6);
    int lane = threadIdx.x & 63;
    const float* x; float* inv; int r;
    if (row < NB * LL) { x = x1; inv = inv1; r = row; }
    else               { x = x2; inv = inv2; r = row - NB * LL; }
    const f32x4* p = reinterpret_cast<const f32x4*>(x + (size_t)r * DD);
    f32x4 a = p[lane];
    f32x4 c = p[lane + 64];
    float ss = a.x*a.x + a.y*a.y + a.z*a.z + a.w*a.w
             + c.x*c.x + c.y*c.y + c.z*c.z + c.w*c.w;
    #pragma unroll
    for (int off = 32; off >= 1; off >>= 1) ss += __shfl_xor(ss, off, 64);
    if (lane == 0) inv[r] = 1.0f / fmaxf(sqrtf(ss), 1e-8f);
}

__global__ __launch_bounds__(256) void init_kernel(unsigned* __restrict__ p, int n) {
    int i = blockIdx.x * 256 + threadIdx.x;
    if (i < n) p[i] = 0u;  // 0 < fmap(-inf) = 0x007FFFFF, identity for real-valued max
}

// stage 64 rows x 512 cols: fp32 global -> normalized bf16 in LDS, XOR-swizzled
__device__ __forceinline__ void stage_tile(
        const float* __restrict__ src, const float* __restrict__ inv,
        char* ldsb, int tid) {
    #pragma unroll
    for (int c = 0; c < 32; ++c) {
        int idx4 = c * 256 + tid;          // float4 index within the 64x512 tile
        int row  = idx4 >> 7;              // 128 float4 per row
        int k4   = idx4 & 127;
        f32x4 v  = *reinterpret_cast<const f32x4*>(src + (size_t)row * DD + (size_t)k4 * 4);
        float s  = inv[row];
        s16x4 o;
        o.x = f2bf(v.x * s); o.y = f2bf(v.y * s);
        o.z = f2bf(v.z * s); o.w = f2bf(v.w * s);
        unsigned byte = (unsigned)((row << 10) + (k4 << 3)) ^ ((unsigned)(row & 7) << 4);
        *reinterpret_cast<s16x4*>(ldsb + byte) = o;
    }
}

__global__ __launch_bounds__(256) void sim_kernel(
        const float* __restrict__ x1, const float* __restrict__ x2,
        const int* __restrict__ mask1, const int* __restrict__ mask2,
        const float* __restrict__ inv1, const float* __restrict__ inv2,
        unsigned* __restrict__ rowmax_u, unsigned* __restrict__ colmax_u) {
    __shared__ __align__(16) char As[BM * DD * 2];
    __shared__ __align__(16) char Bs[BM * DD * 2];

    int bid = blockIdx.x;
    int b   = bid >> 3;
    int i0  = (bid & 7) * BM;
    int tid  = threadIdx.x;
    int lane = tid & 63;
    int w    = tid >> 6;
    int wr = w >> 1, wc = w & 1;
    int l15 = lane & 15, lhi = lane >> 4;

    const float* x1b   = x1 + ((size_t)b * LL + i0) * DD;
    const float* x2b   = x2 + (size_t)b * LL * DD;
    const float* inv1b = inv1 + b * LL + i0;
    const float* inv2b = inv2 + b * LL;

    stage_tile(x1b, inv1b, As, tid);
    stage_tile(x2b, inv2b, Bs, tid);   // chunk 0 = sim-cols 0..63 = rows 0..63 of x2
    __syncthreads();

    // preload this wave's A fragments for the whole K (16 k-steps x 2 row-frags)
    s16x8 af[2][16];
    #pragma unroll
    for (int fr = 0; fr < 2; ++fr) {
        int ar = wr * 32 + fr * 16 + l15;
        unsigned rb = (unsigned)(ar << 10);
        unsigned sw = (unsigned)(ar & 7) << 4;
        #pragma unroll
        for (int ks = 0; ks < 16; ++ks) {
            unsigned byte = (rb + (unsigned)(ks * 64 + lhi * 16)) ^ sw;
            af[fr][ks] = *reinterpret_cast<const s16x8*>(As + byte);
        }
    }

    int m1r[2][4];
    #pragma unroll
    for (int fr = 0; fr < 2; ++fr)
        #pragma unroll
        for (int r = 0; r < 4; ++r)
            m1r[fr][r] = mask1[b * LL + i0 + wr * 32 + fr * 16 + lhi * 4 + r];

    float rm[2][4];
    #pragma unroll
    for (int fr = 0; fr < 2; ++fr)
        #pragma unroll
        for (int r = 0; r < 4; ++r) rm[fr][r] = -INFINITY;

    for (int ch = 0; ch < 8; ++ch) {
        f32x4 acc[2][2];
        #pragma unroll
        for (int fr = 0; fr < 2; ++fr)
            #pragma unroll
            for (int fc = 0; fc < 2; ++fc) {
                acc[fr][fc].x = 0.f; acc[fr][fc].y = 0.f;
                acc[fr][fc].z = 0.f; acc[fr][fc].w = 0.f;
            }

        #pragma unroll
        for (int ks = 0; ks < 16; ++ks) {
            s16x8 bfr[2];
            #pragma unroll
            for (int fc = 0; fc < 2; ++fc) {
                int colt = wc * 32 + fc * 16 + l15;
                unsigned byte = ((unsigned)(colt << 10) + (unsigned)(ks * 64 + lhi * 16))
                              ^ ((unsigned)(colt & 7) << 4);
                bfr[fc] = *reinterpret_cast<const s16x8*>(Bs + byte);
            }
            #pragma unroll
            for (int fr = 0; fr < 2; ++fr)
                #pragma unroll
                for (int fc = 0; fc < 2; ++fc)
                    acc[fr][fc] = __builtin_amdgcn_mfma_f32_16x16x32_bf16(
                        af[fr][ks], bfr[fc], acc[fr][fc], 0, 0, 0);
        }

        int j0 = ch * 64;
        #pragma unroll
        for (int fc = 0; fc < 2; ++fc) {
            int col = j0 + wc * 32 + fc * 16 + l15;
            int m2  = mask2[b * LL + col];
            float cmax = -INFINITY;
            #pragma unroll
            for (int fr = 0; fr < 2; ++fr) {
                #pragma unroll
                for (int r = 0; r < 4; ++r) {
                    float v = acc[fr][fc][r];
                    if (m2)         rm[fr][r] = fmaxf(rm[fr][r], v);
                    if (m1r[fr][r]) cmax      = fmaxf(cmax, v);
                }
            }
            cmax = fmaxf(cmax, __shfl_xor(cmax, 16, 64));
            cmax = fmaxf(cmax, __shfl_xor(cmax, 32, 64));
            if (lhi == 0) atomicMax(&colmax_u[b * LL + col], fmap(cmax));
        }

        __syncthreads();
        if (ch + 1 < 8) {
            stage_tile(x2b + (size_t)(ch + 1) * 64 * DD, inv2b + (ch + 1) * 64, Bs, tid);
            __syncthreads();
        }
    }

    // rowmax: reduce across the 16 col-lanes, then device atomic (2 waves share rows)
    #pragma unroll
    for (int fr = 0; fr < 2; ++fr) {
        #pragma unroll
        for (int r = 0; r < 4; ++r) {
            float v = rm[fr][r];
            v = fmaxf(v, __shfl_xor(v, 1, 64));
            v = fmaxf(v, __shfl_xor(v, 2, 64));
            v = fmaxf(v, __shfl_xor(v, 4, 64));
            v = fmaxf(v, __shfl_xor(v, 8, 64));
            if (l15 == 0)
                atomicMax(&rowmax_u[b * LL + i0 + wr * 32 + fr * 16 + lhi * 4 + r], fmap(v));
        }
    }
}

__global__ __launch_bounds__(64) void finalize_kernel(
        const unsigned* __restrict__ rowmax_u, const unsigned* __restrict__ colmax_u,
        const int* __restrict__ mask1, const int* __restrict__ mask2,
        float* __restrict__ out) {
    int b = blockIdx.x;
    int lane = threadIdx.x;
    float s1 = 0.f, c1 = 0.f, s2 = 0.f, c2 = 0.f;
    for (int i = lane; i < LL; i += 64) {
        if (mask1[b * LL + i]) { s1 += funmap(rowmax_u[b * LL + i]); c1 += 1.f; }
        if (mask2[b * LL + i]) { s2 += funmap(colmax_u[b * LL + i]); c2 += 1.f; }
    }
    #pragma unroll
    for (int off = 32; off >= 1; off >>= 1) {
        s1 += __shfl_xor(s1, off, 64);
        c1 += __shfl_xor(c1, off, 64);
        s2 += __shfl_xor(s2, off, 64);
        c2 += __shfl_xor(c2, off, 64);
    }
    if (lane == 0) out[b] = 0.5f * (s1 / c1 + s2 / c2);
}

extern "C" void kernel_launch(void* const* d_in, const int* in_sizes, int n_in,
                              void* d_out, int out_size, void* d_ws, size_t ws_size,
                              hipStream_t stream) {
    const float* x1    = (const float*)d_in[0];
    const int*   mask1 = (const int*)d_in[1];
    const float* x2    = (const float*)d_in[2];
    const int*   mask2 = (const int*)d_in[3];
    float* out = (float*)d_out;

    float* ws = (float*)d_ws;
    float* inv1 = ws;
    float* inv2 = ws + NB * LL;
    unsigned* rowmax_u = (unsigned*)(ws + 2 * NB * LL);
    unsigned* colmax_u = (unsigned*)(ws + 3 * NB * LL);

    norms_kernel<<<2 * NB * LL / 4, 256, 0, stream>>>(x1, x2, inv1, inv2);
    init_kernel<<<(2 * NB * LL + 255) / 256, 256, 0, stream>>>(rowmax_u, 2 * NB * LL);
    sim_kernel<<<NB * 8, 256, 0, stream>>>(x1, x2, mask1, mask2, inv1, inv2,
                                           rowmax_u, colmax_u);
    finalize_kernel<<<NB, 64, 0, stream>>>(rowmax_u, colmax_u, mask1, mask2, out);
}

// Round 2
// 141.762 us; speedup vs baseline: 2.9312x; 2.9312x over previous
//
#include <hip/hip_runtime.h>
#include <hip/hip_bf16.h>

#define NB 128
#define LL 512
#define DD 512
#define BM 64

#define BMT 128
#define BNT 128
#define BKT 64

typedef __attribute__((ext_vector_type(4))) float  f32x4;
typedef __attribute__((ext_vector_type(8))) short  s16x8;
typedef __attribute__((ext_vector_type(4))) short  s16x4;

#define AS1 __attribute__((address_space(1)))
#define AS3 __attribute__((address_space(3)))

__device__ __forceinline__ short f2bf(float f) {
    __hip_bfloat16 h = __float2bfloat16(f);
    return *reinterpret_cast<short*>(&h);
}

// monotone float<->uint mapping so atomicMax(uint) == float max
__device__ __forceinline__ unsigned fmap(float f) {
    unsigned u = __float_as_uint(f);
    return (u & 0x80000000u) ? ~u : (u | 0x80000000u);
}
__device__ __forceinline__ float funmap(unsigned u) {
    unsigned b = (u & 0x80000000u) ? (u ^ 0x80000000u) : ~u;
    return __uint_as_float(b);
}

__device__ __forceinline__ void gl16(const void* g, void* l) {
    __builtin_amdgcn_global_load_lds((const AS1 unsigned int*)g,
                                     (AS3 unsigned int*)l, 16, 0, 0);
}

// ---------------- new path: precompute normalized bf16 ----------------

// one wave per row: fp32 sum-of-squares -> write normalized bf16 row
__global__ __launch_bounds__(256) void normalize_kernel(
        const float* __restrict__ x1, const float* __restrict__ x2,
        short* __restrict__ n1, short* __restrict__ n2) {
    int row  = blockIdx.x * 4 + (threadIdx.x >> 6);
    int lane = threadIdx.x & 63;
    const float* x; short* n; int r;
    if (row < NB * LL) { x = x1; n = n1; r = row; }
    else               { x = x2; n = n2; r = row - NB * LL; }
    const f32x4* p = reinterpret_cast<const f32x4*>(x + (size_t)r * DD);
    f32x4 a = p[2 * lane];
    f32x4 c = p[2 * lane + 1];
    float ss = a.x*a.x + a.y*a.y + a.z*a.z + a.w*a.w
             + c.x*c.x + c.y*c.y + c.z*c.z + c.w*c.w;
    #pragma unroll
    for (int off = 32; off >= 1; off >>= 1) ss += __shfl_xor(ss, off, 64);
    float s = 1.0f / fmaxf(sqrtf(ss), 1e-8f);
    s16x8 o;
    o[0] = f2bf(a.x * s); o[1] = f2bf(a.y * s);
    o[2] = f2bf(a.z * s); o[3] = f2bf(a.w * s);
    o[4] = f2bf(c.x * s); o[5] = f2bf(c.y * s);
    o[6] = f2bf(c.z * s); o[7] = f2bf(c.w * s);
    reinterpret_cast<s16x8*>(n + (size_t)r * DD)[lane] = o;
}

__global__ __launch_bounds__(256) void init_kernel(unsigned* __restrict__ p, int n) {
    int i = blockIdx.x * 256 + threadIdx.x;
    if (i < n) p[i] = 0u;
}

// stage 128 rows x 64 k (bf16) into a 16 KB LDS buffer, linear dest +
// inverse-swizzled global source (rule 21): logical byte = linear ^ ((row&7)<<4)
__device__ __forceinline__ void stage128x64(
        const short* __restrict__ src, int k0, char* ldsb, int w, int lane) {
    #pragma unroll
    for (int j = 0; j < 4; ++j) {
        int L   = (j * 4 + w) * 1024 + lane * 16;   // linear LDS byte offset
        int row = L >> 7;                           // 128 B per row
        int kg  = ((L >> 4) & 7) ^ (row & 7);       // inverse swizzle on source
        const short* g = src + (size_t)row * DD + k0 + kg * 8;
        gl16(g, ldsb + (j * 4 + w) * 1024);         // HW adds lane*16
    }
}

__global__ __launch_bounds__(256) void simgemm_kernel(
        const short* __restrict__ n1, const short* __restrict__ n2,
        const int* __restrict__ mask1, const int* __restrict__ mask2,
        unsigned* __restrict__ rowmax_u, unsigned* __restrict__ colmax_u) {
    __shared__ __align__(16) char lds[65536];
    // layout: A0 @0, B0 @16384, A1 @32768, B1 @49152

    int bid = blockIdx.x;
    int lid = (bid & 7) * 256 + (bid >> 3);   // XCD-chunked bijective swizzle (nwg=2048)
    int b   = lid >> 4;
    int tr  = (lid >> 2) & 3;
    int tc  = lid & 3;

    int tid  = threadIdx.x;
    int lane = tid & 63;
    int w    = tid >> 6;
    int wr = w >> 1, wc = w & 1;
    int l15 = lane & 15, lhi = lane >> 4;

    const short* Abase = n1 + ((size_t)b * LL + tr * BMT) * DD;
    const short* Bbase = n2 + ((size_t)b * LL + tc * BNT) * DD;

    f32x4 acc[4][4];
    #pragma unroll
    for (int fr = 0; fr < 4; ++fr)
        #pragma unroll
        for (int fc = 0; fc < 4; ++fc) {
            acc[fr][fc].x = 0.f; acc[fr][fc].y = 0.f;
            acc[fr][fc].z = 0.f; acc[fr][fc].w = 0.f;
        }

    // prologue: stage K-tile 0 into buffer 0
    stage128x64(Abase, 0, lds,         w, lane);
    stage128x64(Bbase, 0, lds + 16384, w, lane);
    __syncthreads();

    int cur = 0;
    for (int t = 0; t < 8; ++t) {
        // issue next-tile loads first so they fly under ds_read+MFMA
        if (t < 7) {
            char* nb = lds + (cur ^ 1) * 32768;
            stage128x64(Abase, (t + 1) * BKT, nb,         w, lane);
            stage128x64(Bbase, (t + 1) * BKT, nb + 16384, w, lane);
        }
        char* As = lds + cur * 32768;
        char* Bs = As + 16384;
        #pragma unroll
        for (int ks = 0; ks < 2; ++ks) {
            s16x8 af[4], bf[4];
            #pragma unroll
            for (int fr = 0; fr < 4; ++fr) {
                int row = wr * 64 + fr * 16 + l15;
                unsigned byte = (unsigned)(row * 128 + ks * 64 + lhi * 16)
                              ^ ((unsigned)(row & 7) << 4);
                af[fr] = *reinterpret_cast<const s16x8*>(As + byte);
            }
            #pragma unroll
            for (int fc = 0; fc < 4; ++fc) {
                int crow = wc * 64 + fc * 16 + l15;
                unsigned byte = (unsigned)(crow * 128 + ks * 64 + lhi * 16)
                              ^ ((unsigned)(crow & 7) << 4);
                bf[fc] = *reinterpret_cast<const s16x8*>(Bs + byte);
            }
            #pragma unroll
            for (int fr = 0; fr < 4; ++fr)
                #pragma unroll
                for (int fc = 0; fc < 4; ++fc)
                    acc[fr][fc] = __builtin_amdgcn_mfma_f32_16x16x32_bf16(
                        af[fr], bf[fc], acc[fr][fc], 0, 0, 0);
        }
        __syncthreads();   // drains vmcnt (stage done) + all reads of cur done
        cur ^= 1;
    }

    // ---- epilogue: masked row/col maxes ----
    int m2[4];
    #pragma unroll
    for (int fc = 0; fc < 4; ++fc)
        m2[fc] = mask2[b * LL + tc * BNT + wc * 64 + fc * 16 + l15];
    int m1[4][4];
    #pragma unroll
    for (int fr = 0; fr < 4; ++fr)
        #pragma unroll
        for (int r = 0; r < 4; ++r)
            m1[fr][r] = mask1[b * LL + tr * BMT + wr * 64 + fr * 16 + lhi * 4 + r];

    // row max: per (fr,r) max over this wave's 64 cols (mask2-gated)
    #pragma unroll
    for (int fr = 0; fr < 4; ++fr) {
        #pragma unroll
        for (int r = 0; r < 4; ++r) {
            float v = -INFINITY;
            #pragma unroll
            for (int fc = 0; fc < 4; ++fc)
                if (m2[fc]) v = fmaxf(v, acc[fr][fc][r]);
            v = fmaxf(v, __shfl_xor(v, 1, 64));
            v = fmaxf(v, __shfl_xor(v, 2, 64));
            v = fmaxf(v, __shfl_xor(v, 4, 64));
            v = fmaxf(v, __shfl_xor(v, 8, 64));
            if (l15 == 0)
                atomicMax(&rowmax_u[b * LL + tr * BMT + wr * 64 + fr * 16 + lhi * 4 + r],
                          fmap(v));
        }
    }
    // col max: per fc col, max over this wave's 64 rows (mask1-gated)
    #pragma unroll
    for (int fc = 0; fc < 4; ++fc) {
        float v = -INFINITY;
        #pragma unroll
        for (int fr = 0; fr < 4; ++fr)
            #pragma unroll
            for (int r = 0; r < 4; ++r)
                if (m1[fr][r]) v = fmaxf(v, acc[fr][fc][r]);
        v = fmaxf(v, __shfl_xor(v, 16, 64));
        v = fmaxf(v, __shfl_xor(v, 32, 64));
        if (lhi == 0)
            atomicMax(&colmax_u[b * LL + tc * BNT + wc * 64 + fc * 16 + l15], fmap(v));
    }
}

__global__ __launch_bounds__(64) void finalize_kernel(
        const unsigned* __restrict__ rowmax_u, const unsigned* __restrict__ colmax_u,
        const int* __restrict__ mask1, const int* __restrict__ mask2,
        float* __restrict__ out) {
    int b = blockIdx.x;
    int lane = threadIdx.x;
    float s1 = 0.f, c1 = 0.f, s2 = 0.f, c2 = 0.f;
    for (int i = lane; i < LL; i += 64) {
        if (mask1[b * LL + i]) { s1 += funmap(rowmax_u[b * LL + i]); c1 += 1.f; }
        if (mask2[b * LL + i]) { s2 += funmap(colmax_u[b * LL + i]); c2 += 1.f; }
    }
    #pragma unroll
    for (int off = 32; off >= 1; off >>= 1) {
        s1 += __shfl_xor(s1, off, 64);
        c1 += __shfl_xor(c1, off, 64);
        s2 += __shfl_xor(s2, off, 64);
        c2 += __shfl_xor(c2, off, 64);
    }
    if (lane == 0) out[b] = 0.5f * (s1 / c1 + s2 / c2);
}

// ---------------- fallback path (round-1 kernels, ~1 MB ws) ----------------

__global__ __launch_bounds__(256) void norms_kernel(
        const float* __restrict__ x1, const float* __restrict__ x2,
        float* __restrict__ inv1, float* __restrict__ inv2) {
    int row  = blockIdx.x * 4 + (threadIdx.x >> 6);
    int lane = threadIdx.x & 63;
    const float* x; float* inv; int r;
    if (row < NB * LL) { x = x1; inv = inv1; r = row; }
    else               { x = x2; inv = inv2; r = row - NB * LL; }
    const f32x4* p = reinterpret_cast<const f32x4*>(x + (size_t)r * DD);
    f32x4 a = p[lane];
    f32x4 c = p[lane + 64];
    float ss = a.x*a.x + a.y*a.y + a.z*a.z + a.w*a.w
             + c.x*c.x + c.y*c.y + c.z*c.z + c.w*c.w;
    #pragma unroll
    for (int off = 32; off >= 1; off >>= 1) ss += __shfl_xor(ss, off, 64);
    if (lane == 0) inv[r] = 1.0f / fmaxf(sqrtf(ss), 1e-8f);
}

__device__ __forceinline__ void stage_tile_old(
        const float* __restrict__ src, const float* __restrict__ inv,
        char* ldsb, int tid) {
    #pragma unroll
    for (int c = 0; c < 32; ++c) {
        int idx4 = c * 256 + tid;
        int row  = idx4 >> 7;
        int k4   = idx4 & 127;
        f32x4 v  = *reinterpret_cast<const f32x4*>(src + (size_t)row * DD + (size_t)k4 * 4);
        float s  = inv[row];
        s16x4 o;
        o.x = f2bf(v.x * s); o.y = f2bf(v.y * s);
        o.z = f2bf(v.z * s); o.w = f2bf(v.w * s);
        unsigned byte = (unsigned)((row << 10) + (k4 << 3)) ^ ((unsigned)(row & 7) << 4);
        *reinterpret_cast<s16x4*>(ldsb + byte) = o;
    }
}

__global__ __launch_bounds__(256) void sim_kernel_old(
        const float* __restrict__ x1, const float* __restrict__ x2,
        const int* __restrict__ mask1, const int* __restrict__ mask2,
        const float* __restrict__ inv1, const float* __restrict__ inv2,
        unsigned* __restrict__ rowmax_u, unsigned* __restrict__ colmax_u) {
    __shared__ __align__(16) char As[BM * DD * 2];
    __shared__ __align__(16) char Bs[BM * DD * 2];

    int bid = blockIdx.x;
    int b   = bid >> 3;
    int i0  = (bid & 7) * BM;
    int tid  = threadIdx.x;
    int lane = tid & 63;
    int w    = tid >> 6;
    int wr = w >> 1, wc = w & 1;
    int l15 = lane & 15, lhi = lane >> 4;

    const float* x1b   = x1 + ((size_t)b * LL + i0) * DD;
    const float* x2b   = x2 + (size_t)b * LL * DD;
    const float* inv1b = inv1 + b * LL + i0;
    const float* inv2b = inv2 + b * LL;

    stage_tile_old(x1b, inv1b, As, tid);
    stage_tile_old(x2b, inv2b, Bs, tid);
    __syncthreads();

    s16x8 af[2][16];
    #pragma unroll
    for (int fr = 0; fr < 2; ++fr) {
        int ar = wr * 32 + fr * 16 + l15;
        unsigned rb = (unsigned)(ar << 10);
        unsigned sw = (unsigned)(ar & 7) << 4;
        #pragma unroll
        for (int ks = 0; ks < 16; ++ks) {
            unsigned byte = (rb + (unsigned)(ks * 64 + lhi * 16)) ^ sw;
            af[fr][ks] = *reinterpret_cast<const s16x8*>(As + byte);
        }
    }

    int m1r[2][4];
    #pragma unroll
    for (int fr = 0; fr < 2; ++fr)
        #pragma unroll
        for (int r = 0; r < 4; ++r)
            m1r[fr][r] = mask1[b * LL + i0 + wr * 32 + fr * 16 + lhi * 4 + r];

    float rm[2][4];
    #pragma unroll
    for (int fr = 0; fr < 2; ++fr)
        #pragma unroll
        for (int r = 0; r < 4; ++r) rm[fr][r] = -INFINITY;

    for (int ch = 0; ch < 8; ++ch) {
        f32x4 acc[2][2];
        #pragma unroll
        for (int fr = 0; fr < 2; ++fr)
            #pragma unroll
            for (int fc = 0; fc < 2; ++fc) {
                acc[fr][fc].x = 0.f; acc[fr][fc].y = 0.f;
                acc[fr][fc].z = 0.f; acc[fr][fc].w = 0.f;
            }

        #pragma unroll
        for (int ks = 0; ks < 16; ++ks) {
            s16x8 bfr[2];
            #pragma unroll
            for (int fc = 0; fc < 2; ++fc) {
                int colt = wc * 32 + fc * 16 + l15;
                unsigned byte = ((unsigned)(colt << 10) + (unsigned)(ks * 64 + lhi * 16))
                              ^ ((unsigned)(colt & 7) << 4);
                bfr[fc] = *reinterpret_cast<const s16x8*>(Bs + byte);
            }
            #pragma unroll
            for (int fr = 0; fr < 2; ++fr)
                #pragma unroll
                for (int fc = 0; fc < 2; ++fc)
                    acc[fr][fc] = __builtin_amdgcn_mfma_f32_16x16x32_bf16(
                        af[fr][ks], bfr[fc], acc[fr][fc], 0, 0, 0);
        }

        int j0 = ch * 64;
        #pragma unroll
        for (int fc = 0; fc < 2; ++fc) {
            int col = j0 + wc * 32 + fc * 16 + l15;
            int m2  = mask2[b * LL + col];
            float cmax = -INFINITY;
            #pragma unroll
            for (int fr = 0; fr < 2; ++fr) {
                #pragma unroll
                for (int r = 0; r < 4; ++r) {
                    float v = acc[fr][fc][r];
                    if (m2)         rm[fr][r] = fmaxf(rm[fr][r], v);
                    if (m1r[fr][r]) cmax      = fmaxf(cmax, v);
                }
            }
            cmax = fmaxf(cmax, __shfl_xor(cmax, 16, 64));
            cmax = fmaxf(cmax, __shfl_xor(cmax, 32, 64));
            if (lhi == 0) atomicMax(&colmax_u[b * LL + col], fmap(cmax));
        }

        __syncthreads();
        if (ch + 1 < 8) {
            stage_tile_old(x2b + (size_t)(ch + 1) * 64 * DD, inv2b + (ch + 1) * 64, Bs, tid);
            __syncthreads();
        }
    }

    #pragma unroll
    for (int fr = 0; fr < 2; ++fr) {
        #pragma unroll
        for (int r = 0; r < 4; ++r) {
            float v = rm[fr][r];
            v = fmaxf(v, __shfl_xor(v, 1, 64));
            v = fmaxf(v, __shfl_xor(v, 2, 64));
            v = fmaxf(v, __shfl_xor(v, 4, 64));
            v = fmaxf(v, __shfl_xor(v, 8, 64));
            if (l15 == 0)
                atomicMax(&rowmax_u[b * LL + i0 + wr * 32 + fr * 16 + lhi * 4 + r], fmap(v));
        }
    }
}

extern "C" void kernel_launch(void* const* d_in, const int* in_sizes, int n_in,
                              void* d_out, int out_size, void* d_ws, size_t ws_size,
                              hipStream_t stream) {
    const float* x1    = (const float*)d_in[0];
    const int*   mask1 = (const int*)d_in[1];
    const float* x2    = (const float*)d_in[2];
    const int*   mask2 = (const int*)d_in[3];
    float* out = (float*)d_out;

    size_t nElem = (size_t)NB * LL * DD;               // 33.5 M
    size_t need  = 2 * nElem * sizeof(short) + 2 * (size_t)NB * LL * sizeof(unsigned);

    if (ws_size >= need) {
        short* n1 = (short*)d_ws;
        short* n2 = n1 + nElem;
        unsigned* rowmax_u = (unsigned*)(n2 + nElem);
        unsigned* colmax_u = rowmax_u + NB * LL;

        normalize_kernel<<<2 * NB * LL / 4, 256, 0, stream>>>(x1, x2, n1, n2);
        init_kernel<<<(2 * NB * LL + 255) / 256, 256, 0, stream>>>(rowmax_u, 2 * NB * LL);
        simgemm_kernel<<<NB * 16, 256, 0, stream>>>(n1, n2, mask1, mask2,
                                                    rowmax_u, colmax_u);
        finalize_kernel<<<NB, 64, 0, stream>>>(rowmax_u, colmax_u, mask1, mask2, out);
    } else {
        float* ws = (float*)d_ws;
        float* inv1 = ws;
        float* inv2 = ws + NB * LL;
        unsigned* rowmax_u = (unsigned*)(ws + 2 * NB * LL);
        unsigned* colmax_u = (unsigned*)(ws + 3 * NB * LL);

        norms_kernel<<<2 * NB * LL / 4, 256, 0, stream>>>(x1, x2, inv1, inv2);
        init_kernel<<<(2 * NB * LL + 255) / 256, 256, 0, stream>>>(rowmax_u, 2 * NB * LL);
        sim_kernel_old<<<NB * 8, 256, 0, stream>>>(x1, x2, mask1, mask2, inv1, inv2,
                                                   rowmax_u, colmax_u);
        finalize_kernel<<<NB, 64, 0, stream>>>(rowmax_u, colmax_u, mask1, mask2, out);
    }
}

// Round 3
// 125.886 us; speedup vs baseline: 3.3009x; 1.1261x over previous
//
#include <hip/hip_runtime.h>
#include <hip/hip_bf16.h>

#define NB 128
#define LL 512
#define DD 512

typedef __attribute__((ext_vector_type(4))) float  f32x4;
typedef __attribute__((ext_vector_type(8))) short  s16x8;
typedef __attribute__((ext_vector_type(4))) short  s16x4;

__device__ __forceinline__ short f2bf(float f) {
    __hip_bfloat16 h = __float2bfloat16(f);
    return *reinterpret_cast<short*>(&h);
}

// monotone float<->uint mapping so atomicMax(uint) == float max
__device__ __forceinline__ unsigned fmap(float f) {
    unsigned u = __float_as_uint(f);
    return (u & 0x80000000u) ? ~u : (u | 0x80000000u);
}
__device__ __forceinline__ float funmap(unsigned u) {
    unsigned b = (u & 0x80000000u) ? (u ^ 0x80000000u) : ~u;
    return __uint_as_float(b);
}

__global__ __launch_bounds__(256) void init_kernel(unsigned* __restrict__ p, int n) {
    int i = blockIdx.x * 256 + threadIdx.x;
    if (i < n) p[i] = 0u;  // 0 < fmap of any real value
}

// Fused: normalize (on the fly) + 128x128x512 bf16 GEMM + masked row/col max.
// Staging: fp32 global -> regs -> (sum-of-squares accum, fp32) -> bf16 ->
// XOR-swizzled LDS. Epilogue scales dot by inv-norms before the maxes.
__global__ __launch_bounds__(256, 2) void simgemm_fused(
        const float* __restrict__ x1, const float* __restrict__ x2,
        const int* __restrict__ mask1, const int* __restrict__ mask2,
        unsigned* __restrict__ rowmax_u, unsigned* __restrict__ colmax_u) {
    __shared__ __align__(16) char lds[66560];
    // A0 @0, B0 @16384, A1 @32768, B1 @49152, invA @65536 (128 f32), invB @66048
    float* invA_lds = reinterpret_cast<float*>(lds + 65536);
    float* invB_lds = reinterpret_cast<float*>(lds + 66048);

    int bid = blockIdx.x;
    int lid = (bid & 7) * 256 + (bid >> 3);   // XCD-chunked bijective swizzle (nwg=2048)
    int b   = lid >> 4;
    int tr  = (lid >> 2) & 3;
    int tc  = lid & 3;

    int tid  = threadIdx.x;
    int lane = tid & 63;
    int w    = tid >> 6;
    int wr = w >> 1, wc = w & 1;
    int l15 = lane & 15, lhi = lane >> 4;
    int cg = l15, rg = lhi;                   // staging coords: 16 lanes/row, 4 rows/instr

    const float* Ab = x1 + ((size_t)b * LL + tr * 128) * DD;
    const float* Bb = x2 + ((size_t)b * LL + tc * 128) * DD;

    f32x4 ra[8], rb[8];
    float ssa[8], ssb[8];
    #pragma unroll
    for (int i = 0; i < 8; ++i) { ssa[i] = 0.f; ssb[i] = 0.f; }

    f32x4 acc[4][4];
    #pragma unroll
    for (int fr = 0; fr < 4; ++fr)
        #pragma unroll
        for (int fc = 0; fc < 4; ++fc) {
            acc[fr][fc].x = 0.f; acc[fr][fc].y = 0.f;
            acc[fr][fc].z = 0.f; acc[fr][fc].w = 0.f;
        }

    // each thread stages 8 f32x4 of A and 8 of B per K-tile:
    // row = w*32 + i*4 + rg  (wave w owns rows [w*32, w*32+32)), cols cg*4..cg*4+3
    #define ISSUE(k0)                                                             \
        {                                                                         \
            _Pragma("unroll")                                                     \
            for (int i = 0; i < 8; ++i) {                                         \
                int row = w * 32 + i * 4 + rg;                                    \
                ra[i] = *reinterpret_cast<const f32x4*>(Ab + (size_t)row * DD + (k0) + cg * 4); \
                rb[i] = *reinterpret_cast<const f32x4*>(Bb + (size_t)row * DD + (k0) + cg * 4); \
            }                                                                     \
        }

    #define COMMIT(base)                                                          \
        {                                                                         \
            char* As_ = (base);                                                   \
            char* Bs_ = (base) + 16384;                                           \
            _Pragma("unroll")                                                     \
            for (int i = 0; i < 8; ++i) {                                         \
                int row = w * 32 + i * 4 + rg;                                    \
                unsigned byte = ((unsigned)(row * 128 + cg * 8))                  \
                              ^ ((unsigned)(row & 7) << 4);                       \
                f32x4 va = ra[i];                                                 \
                ssa[i] += va.x*va.x + va.y*va.y + va.z*va.z + va.w*va.w;          \
                s16x4 oa; oa.x = f2bf(va.x); oa.y = f2bf(va.y);                   \
                oa.z = f2bf(va.z); oa.w = f2bf(va.w);                             \
                *reinterpret_cast<s16x4*>(As_ + byte) = oa;                       \
                f32x4 vb = rb[i];                                                 \
                ssb[i] += vb.x*vb.x + vb.y*vb.y + vb.z*vb.z + vb.w*vb.w;          \
                s16x4 ob; ob.x = f2bf(vb.x); ob.y = f2bf(vb.y);                   \
                ob.z = f2bf(vb.z); ob.w = f2bf(vb.w);                             \
                *reinterpret_cast<s16x4*>(Bs_ + byte) = ob;                       \
            }                                                                     \
        }

    // prologue: K-tile 0
    ISSUE(0);
    COMMIT(lds);
    __syncthreads();

    #pragma unroll
    for (int t = 0; t < 8; ++t) {
        if (t < 7) ISSUE((t + 1) * 64);      // in flight under the MFMA phase
        char* As = lds + (t & 1) * 32768;
        char* Bs = As + 16384;
        #pragma unroll
        for (int ks = 0; ks < 2; ++ks) {
            s16x8 af[4], bf[4];
            #pragma unroll
            for (int fr = 0; fr < 4; ++fr) {
                int row = wr * 64 + fr * 16 + l15;
                unsigned byte = (unsigned)(row * 128 + ks * 64 + lhi * 16)
                              ^ ((unsigned)(row & 7) << 4);
                af[fr] = *reinterpret_cast<const s16x8*>(As + byte);
            }
            #pragma unroll
            for (int fc = 0; fc < 4; ++fc) {
                int crow = wc * 64 + fc * 16 + l15;
                unsigned byte = (unsigned)(crow * 128 + ks * 64 + lhi * 16)
                              ^ ((unsigned)(crow & 7) << 4);
                bf[fc] = *reinterpret_cast<const s16x8*>(Bs + byte);
            }
            #pragma unroll
            for (int fr = 0; fr < 4; ++fr)
                #pragma unroll
                for (int fc = 0; fc < 4; ++fc)
                    acc[fr][fc] = __builtin_amdgcn_mfma_f32_16x16x32_bf16(
                        af[fr], bf[fc], acc[fr][fc], 0, 0, 0);
        }
        if (t < 7) {
            COMMIT(lds + ((t + 1) & 1) * 32768);
            __syncthreads();
        }
    }

    // ---- inv norms: reduce SS across the 16 lanes sharing each row ----
    #pragma unroll
    for (int i = 0; i < 8; ++i) {
        #pragma unroll
        for (int off = 1; off <= 8; off <<= 1) {
            ssa[i] += __shfl_xor(ssa[i], off, 64);
            ssb[i] += __shfl_xor(ssb[i], off, 64);
        }
    }
    if (cg == 0) {
        #pragma unroll
        for (int i = 0; i < 8; ++i) {
            int row = w * 32 + i * 4 + rg;
            invA_lds[row] = 1.0f / fmaxf(sqrtf(ssa[i]), 1e-8f);
            invB_lds[row] = 1.0f / fmaxf(sqrtf(ssb[i]), 1e-8f);
        }
    }
    __syncthreads();

    // ---- scale by inv norms ----
    float ia[4][4], ib4[4];
    #pragma unroll
    for (int fr = 0; fr < 4; ++fr)
        #pragma unroll
        for (int r = 0; r < 4; ++r)
            ia[fr][r] = invA_lds[wr * 64 + fr * 16 + lhi * 4 + r];
    #pragma unroll
    for (int fc = 0; fc < 4; ++fc)
        ib4[fc] = invB_lds[wc * 64 + fc * 16 + l15];
    #pragma unroll
    for (int fr = 0; fr < 4; ++fr)
        #pragma unroll
        for (int fc = 0; fc < 4; ++fc)
            #pragma unroll
            for (int r = 0; r < 4; ++r)
                acc[fr][fc][r] *= ia[fr][r] * ib4[fc];

    // ---- epilogue: masked row/col maxes ----
    int m2[4];
    #pragma unroll
    for (int fc = 0; fc < 4; ++fc)
        m2[fc] = mask2[b * LL + tc * 128 + wc * 64 + fc * 16 + l15];
    int m1[4][4];
    #pragma unroll
    for (int fr = 0; fr < 4; ++fr)
        #pragma unroll
        for (int r = 0; r < 4; ++r)
            m1[fr][r] = mask1[b * LL + tr * 128 + wr * 64 + fr * 16 + lhi * 4 + r];

    // row max: per (fr,r) max over this wave's 64 cols (mask2-gated)
    #pragma unroll
    for (int fr = 0; fr < 4; ++fr) {
        #pragma unroll
        for (int r = 0; r < 4; ++r) {
            float v = -INFINITY;
            #pragma unroll
            for (int fc = 0; fc < 4; ++fc)
                if (m2[fc]) v = fmaxf(v, acc[fr][fc][r]);
            v = fmaxf(v, __shfl_xor(v, 1, 64));
            v = fmaxf(v, __shfl_xor(v, 2, 64));
            v = fmaxf(v, __shfl_xor(v, 4, 64));
            v = fmaxf(v, __shfl_xor(v, 8, 64));
            if (l15 == 0)
                atomicMax(&rowmax_u[b * LL + tr * 128 + wr * 64 + fr * 16 + lhi * 4 + r],
                          fmap(v));
        }
    }
    // col max: per fc col, max over this wave's 64 rows (mask1-gated)
    #pragma unroll
    for (int fc = 0; fc < 4; ++fc) {
        float v = -INFINITY;
        #pragma unroll
        for (int fr = 0; fr < 4; ++fr)
            #pragma unroll
            for (int r = 0; r < 4; ++r)
                if (m1[fr][r]) v = fmaxf(v, acc[fr][fc][r]);
        v = fmaxf(v, __shfl_xor(v, 16, 64));
        v = fmaxf(v, __shfl_xor(v, 32, 64));
        if (lhi == 0)
            atomicMax(&colmax_u[b * LL + tc * 128 + wc * 64 + fc * 16 + l15], fmap(v));
    }
    #undef ISSUE
    #undef COMMIT
}

__global__ __launch_bounds__(64) void finalize_kernel(
        const unsigned* __restrict__ rowmax_u, const unsigned* __restrict__ colmax_u,
        const int* __restrict__ mask1, const int* __restrict__ mask2,
        float* __restrict__ out) {
    int b = blockIdx.x;
    int lane = threadIdx.x;
    float s1 = 0.f, c1 = 0.f, s2 = 0.f, c2 = 0.f;
    for (int i = lane; i < LL; i += 64) {
        if (mask1[b * LL + i]) { s1 += funmap(rowmax_u[b * LL + i]); c1 += 1.f; }
        if (mask2[b * LL + i]) { s2 += funmap(colmax_u[b * LL + i]); c2 += 1.f; }
    }
    #pragma unroll
    for (int off = 32; off >= 1; off >>= 1) {
        s1 += __shfl_xor(s1, off, 64);
        c1 += __shfl_xor(c1, off, 64);
        s2 += __shfl_xor(s2, off, 64);
        c2 += __shfl_xor(c2, off, 64);
    }
    if (lane == 0) out[b] = 0.5f * (s1 / c1 + s2 / c2);
}

extern "C" void kernel_launch(void* const* d_in, const int* in_sizes, int n_in,
                              void* d_out, int out_size, void* d_ws, size_t ws_size,
                              hipStream_t stream) {
    const float* x1    = (const float*)d_in[0];
    const int*   mask1 = (const int*)d_in[1];
    const float* x2    = (const float*)d_in[2];
    const int*   mask2 = (const int*)d_in[3];
    float* out = (float*)d_out;

    unsigned* rowmax_u = (unsigned*)d_ws;
    unsigned* colmax_u = rowmax_u + NB * LL;

    init_kernel<<<(2 * NB * LL + 255) / 256, 256, 0, stream>>>(rowmax_u, 2 * NB * LL);
    simgemm_fused<<<NB * 16, 256, 0, stream>>>(x1, x2, mask1, mask2,
                                               rowmax_u, colmax_u);
    finalize_kernel<<<NB, 64, 0, stream>>>(rowmax_u, colmax_u, mask1, mask2, out);
}